// Round 1
// baseline (37.991 us; speedup 1.0000x reference)
//
#include <hip/hip_runtime.h>

// Problem constants (from reference):
//   BLOCK 8x8, IMG 256x512, NBLOCKS=256, TILES=2048, BATCH=16, NSEQ=256, TAU=1
//   out[b,h,w] = deblock( 2 * sum_n softmax(seq[f[b],t]+gum[b,t])[n] * blocks[n,h%8,w%8] ) / 2
//   with t = (h/8)*64 + (w/8).
// The deblocking filter is purely row-local (both reference passes slice the
// LAST axis; pass-2's x-arg is the ORIGINAL img, not pass-1 output), so one
// workgroup per (b, hb) tile-row computes 8 rows x 512 cols end-to-end.

#define NB   256   // NBLOCKS
#define TIL  2048  // TILES
#define EP   260   // LDS pitch for E rows (float4-aligned, de-aliased banks)

__device__ __forceinline__ float trilerp(const float* __restrict__ lutS,
                                         float x, float y, float z) {
    // x0 = clip(floor(x),0,1); x1 = x0+1 (<=2); xd = x - x0 (UNclamped) — per ref
    int x0 = (int)fminf(fmaxf(floorf(x), 0.0f), 1.0f);
    int y0 = (int)fminf(fmaxf(floorf(y), 0.0f), 1.0f);
    int z0 = (int)fminf(fmaxf(floorf(z), 0.0f), 1.0f);
    float xd = x - (float)x0;
    float yd = y - (float)y0;
    float zd = z - (float)z0;
    int base = x0 * 9 + y0 * 3 + z0;          // lut[x,y,z] flat = x*9+y*3+z
    float c000 = lutS[base];
    float c100 = lutS[base + 9];
    float c010 = lutS[base + 3];
    float c110 = lutS[base + 12];
    float c001 = lutS[base + 1];
    float c101 = lutS[base + 10];
    float c011 = lutS[base + 4];
    float c111 = lutS[base + 13];
    float xm = 1.0f - xd, ym = 1.0f - yd;
    float c00 = c000 * xm * ym + c100 * xd * ym + c010 * xm * yd + c110 * xd * yd;
    float c01 = c001 * xm * ym + c101 * xd * ym + c011 * xm * yd + c111 * xd * yd;
    return c00 * (1.0f - zd) + c01 * zd;
}

__global__ __launch_bounds__(256, 2)
void ImageReconstruction_46523085751029_kernel(
        const float* __restrict__ seq,      // [256][2048][256]
        const float* __restrict__ blocks,   // [256][64]
        const float* __restrict__ lut,      // [27]
        const float* __restrict__ gumbel,   // [16][2048][256]
        const int*   __restrict__ fidx,     // [16]
        float*       __restrict__ out)      // [16][256][512]
{
    __shared__ float E[64 * EP];   // 66560 B; later aliased: rows_img[8*512], rows_f[8*512]
    __shared__ float pden[64 * 4];
    __shared__ float rden[64];
    __shared__ float lutS[28];

    const int t  = threadIdx.x;
    const int b  = blockIdx.x >> 5;   // 0..15
    const int hb = blockIdx.x & 31;   // 0..31

    if (t < 27) lutS[t] = lut[t];

    const int f = fidx[b];
    const float* sp = seq    + (size_t)f * (TIL * NB) + (size_t)hb * (64 * NB);
    const float* gp = gumbel + (size_t)b * (TIL * NB) + (size_t)hb * (64 * NB);

    // ---- Phase 1: E[wb][n] = exp(logit + gumbel)  (no max-sub: |x| <= ~22, safe in f32)
    #pragma unroll
    for (int r = 0; r < 16; ++r) {
        int flat = (r * 256 + t) * 4;                 // 0..16380, step 4, all covered
        float4 l4 = *(const float4*)(sp + flat);
        float4 g4 = *(const float4*)(gp + flat);
        int wb = flat >> 8;
        int n  = flat & 255;
        float4 e4 = make_float4(__expf(l4.x + g4.x), __expf(l4.y + g4.y),
                                __expf(l4.z + g4.z), __expf(l4.w + g4.w));
        *(float4*)&E[wb * EP + n] = e4;               // 16B-aligned: 260*4 and n*4 are %16==0
    }
    __syncthreads();

    // ---- Phase 1.5: denominators (per-tile sum of exp), then reciprocal
    {
        int wb = t >> 2, q = t & 3;
        const float* e = &E[wb * EP + q * 64];
        float s = 0.0f;
        #pragma unroll
        for (int m = 0; m < 16; ++m) {
            float4 v = *(const float4*)(e + 4 * m);
            s += (v.x + v.y) + (v.z + v.w);
        }
        pden[t] = s;
    }
    __syncthreads();
    if (t < 64) {
        float4 v = *(const float4*)&pden[t * 4];
        rden[t] = 1.0f / ((v.x + v.y) + (v.z + v.w));
    }
    __syncthreads();

    // ---- Phase 2: per-thread 4 tiles x 4 outputs, n-vectorized by 4
    const int wb0 = (t >> 4) * 4;   // tile group
    const int k0  = (t & 15) * 4;   // output (bh*8+bw) group
    float acc[4][4] = {{0.0f}};

    #pragma unroll 2
    for (int n = 0; n < NB; n += 4) {
        float4 e4[4], bk[4];
        #pragma unroll
        for (int i = 0; i < 4; ++i)
            e4[i] = *(const float4*)&E[(wb0 + i) * EP + n];
        #pragma unroll
        for (int m = 0; m < 4; ++m)
            bk[m] = *(const float4*)(blocks + (n + m) * 64 + k0);
        #pragma unroll
        for (int i = 0; i < 4; ++i) {
            #pragma unroll
            for (int j = 0; j < 4; ++j) {
                float bj0 = ((const float*)&bk[0])[j];
                float bj1 = ((const float*)&bk[1])[j];
                float bj2 = ((const float*)&bk[2])[j];
                float bj3 = ((const float*)&bk[3])[j];
                acc[i][j] += e4[i].x * bj0 + e4[i].y * bj1
                           + e4[i].z * bj2 + e4[i].w * bj3;
            }
        }
    }

    // normalize and apply img = 2*rec
    float vals[4][4];
    #pragma unroll
    for (int i = 0; i < 4; ++i) {
        float s2 = 2.0f * rden[wb0 + i];
        #pragma unroll
        for (int j = 0; j < 4; ++j) vals[i][j] = acc[i][j] * s2;
    }
    __syncthreads();   // everyone done reading E before aliasing it

    float* rows_img = E;            // [8][512]
    float* rows_f   = E + 4096;     // [8][512]
    #pragma unroll
    for (int i = 0; i < 4; ++i) {
        #pragma unroll
        for (int j = 0; j < 4; ++j) {
            int k  = k0 + j;
            int bh = k >> 3, bw = k & 7;
            int w  = (wb0 + i) * 8 + bw;
            rows_img[bh * 512 + w] = vals[i][j];
        }
    }
    __syncthreads();

    // ---- Pass 1: horizontal filter at w%8 in {0,7}
    #pragma unroll 2
    for (int p = 0; p < 16; ++p) {
        int pix = p * 256 + t;
        int bh = pix >> 9, w = pix & 511;
        float c   = rows_img[bh * 512 + w];
        float res = c;
        int w8 = w & 7;
        if (w8 == 0 || w8 == 7) {
            int wm = (w > 0)   ? w - 1 : 0;
            int wp = (w < 511) ? w + 1 : 511;
            res = trilerp(lutS, c, rows_img[bh * 512 + wm], rows_img[bh * 512 + wp]);
        }
        rows_f[bh * 512 + w] = res;
    }
    __syncthreads();

    // ---- Pass 2 (rows h%8 in {0,7}; x-arg = ORIGINAL img per reference) + store
    float* op = out + (size_t)b * (256 * 512) + (size_t)hb * (8 * 512);
    #pragma unroll 2
    for (int p = 0; p < 16; ++p) {
        int pix = p * 256 + t;
        int bh = pix >> 9, w = pix & 511;
        float g;
        if (bh == 0 || bh == 7) {
            int wm = (w > 0)   ? w - 1 : 0;
            int wp = (w < 511) ? w + 1 : 511;
            g = trilerp(lutS, rows_img[bh * 512 + w],
                        rows_f[bh * 512 + wm], rows_f[bh * 512 + wp]);
        } else {
            g = rows_f[bh * 512 + w];
        }
        op[bh * 512 + w] = 0.5f * g;
    }
}

extern "C" void kernel_launch(void* const* d_in, const int* in_sizes, int n_in,
                              void* d_out, int out_size, void* d_ws, size_t ws_size,
                              hipStream_t stream) {
    const float* seq    = (const float*)d_in[0];
    const float* blocks = (const float*)d_in[1];
    const float* lut    = (const float*)d_in[2];
    const float* gumbel = (const float*)d_in[3];
    const int*   fidx   = (const int*)d_in[4];
    float* out = (float*)d_out;

    dim3 grid(512);   // 16 batches x 32 tile-rows
    dim3 block(256);
    ImageReconstruction_46523085751029_kernel<<<grid, block, 0, stream>>>(
        seq, blocks, lut, gumbel, fidx, out);
}

// Round 2
// 25.067 us; speedup vs baseline: 1.5156x; 1.5156x over previous
//
#include <hip/hip_runtime.h>

// out[b,h,w] = deblock( 2 * softmax(seq[f[b],t]+gum[b,t]) @ blocks ) / 2
// One WG per (b, hb): computes 8 rows x 512 cols end-to-end.
// Matvec done with bf16 MFMA (16x16x32); softmax denominator computed by an
// extra MFMA against a ones-column B operand (den lands in C col 0).
// A- and B-fragments use the SAME lane->(k) formula, so the exact j<->k
// interleave of the HW fragment cancels over the reduction axis; only
// lane&15 <-> M/N and the verified C/D mapping (col=lane&15,
// row=(lane>>4)*4+reg) are relied upon.

#define NB     256
#define TIL    2048
#define EPITCH 264   // ushort pitch for E rows (pad: 264*2=528B, de-aliases banks)

typedef short  s8v __attribute__((ext_vector_type(8)));  // 8 bf16 = 4 VGPR
typedef float  f4v __attribute__((ext_vector_type(4)));  // 4 f32 acc

__device__ __forceinline__ unsigned short f2bf(float f) {
    unsigned int u = __float_as_uint(f);
    u += 0x7fffu + ((u >> 16) & 1u);      // round-to-nearest-even
    return (unsigned short)(u >> 16);
}

__device__ __forceinline__ float trilerp(const float* __restrict__ lutS,
                                         float x, float y, float z) {
    int x0 = (int)fminf(fmaxf(floorf(x), 0.0f), 1.0f);
    int y0 = (int)fminf(fmaxf(floorf(y), 0.0f), 1.0f);
    int z0 = (int)fminf(fmaxf(floorf(z), 0.0f), 1.0f);
    float xd = x - (float)x0;
    float yd = y - (float)y0;
    float zd = z - (float)z0;
    int base = x0 * 9 + y0 * 3 + z0;
    float c000 = lutS[base],     c100 = lutS[base + 9];
    float c010 = lutS[base + 3], c110 = lutS[base + 12];
    float c001 = lutS[base + 1], c101 = lutS[base + 10];
    float c011 = lutS[base + 4], c111 = lutS[base + 13];
    float xm = 1.0f - xd, ym = 1.0f - yd;
    float c00 = c000 * xm * ym + c100 * xd * ym + c010 * xm * yd + c110 * xd * yd;
    float c01 = c001 * xm * ym + c101 * xd * ym + c011 * xm * yd + c111 * xd * yd;
    return c00 * (1.0f - zd) + c01 * zd;
}

__global__ __launch_bounds__(256, 2)
void ImageReconstruction_46523085751029_kernel(
        const float* __restrict__ seq,      // [256][2048][256]
        const float* __restrict__ blocks,   // [256][64]
        const float* __restrict__ lut,      // [27]
        const float* __restrict__ gumbel,   // [16][2048][256]
        const int*   __restrict__ fidx,     // [16]
        float*       __restrict__ out)      // [16][256][512]
{
    __shared__ __align__(16) unsigned short E[64 * EPITCH];  // 33792 B; aliased by rows later
    __shared__ float lutS[28];

    const int t    = threadIdx.x;
    const int lane = t & 63;
    const int wave = t >> 6;          // 0..3 -> pixel tile (N-strip)
    const int b    = blockIdx.x >> 5;
    const int hb   = blockIdx.x & 31;

    if (t < 27) lutS[t] = lut[t];

    const int f = fidx[b];
    const float* sp = seq    + (size_t)f * (TIL * NB) + (size_t)hb * (64 * NB);
    const float* gp = gumbel + (size_t)b * (TIL * NB) + (size_t)hb * (64 * NB);

    // ---- P1: coalesced load + exp + bf16 pack -> E[tile][n]  (no max-sub: |x|<=~22)
    #pragma unroll 4
    for (int r = 0; r < 16; ++r) {
        int fi = r * 256 + t;                       // float4 index, covers 64*256 floats
        float4 l4 = *(const float4*)(sp + fi * 4);
        float4 g4 = *(const float4*)(gp + fi * 4);
        int tile = fi >> 6;
        int n    = (fi & 63) * 4;
        ushort4 st = make_ushort4(f2bf(__expf(l4.x + g4.x)), f2bf(__expf(l4.y + g4.y)),
                                  f2bf(__expf(l4.z + g4.z)), f2bf(__expf(l4.w + g4.w)));
        *(ushort4*)&E[tile * EPITCH + n] = st;      // 8B store, aligned
    }

    // ---- B-fragments from global (once; L2-hot 64 KB), same k-formula as A-frags
    const int g = lane >> 4;       // k-group
    const int c = lane & 15;       // N-index within tile
    s8v bfrag[8];
    #pragma unroll
    for (int ks = 0; ks < 8; ++ks) {
        s8v bf;
        #pragma unroll
        for (int j = 0; j < 8; ++j) {
            float v = blocks[(ks * 32 + g * 8 + j) * 64 + wave * 16 + c];
            bf[j] = (short)f2bf(v);
        }
        bfrag[ks] = bf;
    }
    s8v ones;
    #pragma unroll
    for (int j = 0; j < 8; ++j) ones[j] = (c == 0) ? (short)0x3F80 : (short)0;

    __syncthreads();

    // ---- P2: MFMA. Per wave: N-strip = wave*16..+15, all 4 M-tiles, K=256.
    f4v acc[4], accd[4];
    #pragma unroll
    for (int mt = 0; mt < 4; ++mt) { acc[mt] = (f4v)0.0f; accd[mt] = (f4v)0.0f; }

    #pragma unroll
    for (int ks = 0; ks < 8; ++ks) {
        #pragma unroll
        for (int mt = 0; mt < 4; ++mt) {
            s8v a = *(const s8v*)&E[(mt * 16 + c) * EPITCH + ks * 32 + g * 8];
            acc[mt]  = __builtin_amdgcn_mfma_f32_16x16x32_bf16(a, bfrag[ks], acc[mt],  0, 0, 0);
            accd[mt] = __builtin_amdgcn_mfma_f32_16x16x32_bf16(a, ones,      accd[mt], 0, 0, 0);
        }
    }

    __syncthreads();   // all E reads done; safe to alias

    // ---- normalize (den from accd col 0, broadcast within 16-lane group) -> rows_img
    float* rows_img = (float*)E;            // [8][512] = 16 KB
    float* rows_f   = (float*)E + 4096;     // [8][512] = 16 KB (total 32 KB <= 33792 B)

    #pragma unroll
    for (int mt = 0; mt < 4; ++mt) {
        #pragma unroll
        for (int rg = 0; rg < 4; ++rg) {
            float den = __shfl(accd[mt][rg], (lane >> 4) * 16);  // value at col 0 of this row
            float val = acc[mt][rg] * (2.0f / den);
            int row = mt * 16 + g * 4 + rg;      // tile index wb (0..63)
            int p   = wave * 16 + c;             // pixel 0..63
            int bh  = p >> 3, bw = p & 7;
            rows_img[bh * 512 + row * 8 + bw] = val;
        }
    }
    __syncthreads();

    // ---- Pass 1: horizontal filter at w%8 in {0,7}
    #pragma unroll 2
    for (int pp = 0; pp < 16; ++pp) {
        int pix = pp * 256 + t;
        int bh = pix >> 9, w = pix & 511;
        float cv  = rows_img[bh * 512 + w];
        float res = cv;
        int w8 = w & 7;
        if (w8 == 0 || w8 == 7) {
            int wm = (w > 0)   ? w - 1 : 0;
            int wp = (w < 511) ? w + 1 : 511;
            res = trilerp(lutS, cv, rows_img[bh * 512 + wm], rows_img[bh * 512 + wp]);
        }
        rows_f[bh * 512 + w] = res;
    }
    __syncthreads();

    // ---- Pass 2 (rows h%8 in {0,7}; x-arg = ORIGINAL img per reference) + store
    float* op = out + (size_t)b * (256 * 512) + (size_t)hb * (8 * 512);
    #pragma unroll 2
    for (int pp = 0; pp < 16; ++pp) {
        int pix = pp * 256 + t;
        int bh = pix >> 9, w = pix & 511;
        float gv;
        if (bh == 0 || bh == 7) {
            int wm = (w > 0)   ? w - 1 : 0;
            int wp = (w < 511) ? w + 1 : 511;
            gv = trilerp(lutS, rows_img[bh * 512 + w],
                         rows_f[bh * 512 + wm], rows_f[bh * 512 + wp]);
        } else {
            gv = rows_f[bh * 512 + w];
        }
        op[bh * 512 + w] = 0.5f * gv;
    }
}

extern "C" void kernel_launch(void* const* d_in, const int* in_sizes, int n_in,
                              void* d_out, int out_size, void* d_ws, size_t ws_size,
                              hipStream_t stream) {
    const float* seq    = (const float*)d_in[0];
    const float* blocks = (const float*)d_in[1];
    const float* lut    = (const float*)d_in[2];
    const float* gumbel = (const float*)d_in[3];
    const int*   fidx   = (const int*)d_in[4];
    float* out = (float*)d_out;

    dim3 grid(512);   // 16 batches x 32 tile-rows
    dim3 block(256);
    ImageReconstruction_46523085751029_kernel<<<grid, block, 0, stream>>>(
        seq, blocks, lut, gumbel, fidx, out);
}

// Round 3
// 24.369 us; speedup vs baseline: 1.5590x; 1.0286x over previous
//
#include <hip/hip_runtime.h>

// out[b,h,w] = deblock( 2 * softmax(seq[f[b],t]+gum[b,t]) @ blocks ) / 2
// One WG per (b, hb): computes 8 rows x 512 cols end-to-end.
// 512 threads/WG (8 waves) -> 16 waves/CU at grid=512: doubles latency hiding
// vs the 256-thread version (grid is structurally pinned at 512 WGs).
// Matvec via bf16 MFMA 16x16x32; softmax denominator via an extra MFMA
// against a ones-column B operand (den lands in C col 0).
// A- and B-fragments use the SAME lane->k formula so the HW k-interleave
// cancels over the reduction; relies only on lane&15 <-> M/N and the verified
// C/D mapping (col=lane&15, row=(lane>>4)*4+reg).

#define NB     256
#define TIL    2048
#define EPITCH 264   // ushort pitch (528 B/row)

typedef short  s8v __attribute__((ext_vector_type(8)));  // 8 bf16 = 4 VGPR
typedef float  f4v __attribute__((ext_vector_type(4)));  // 4 f32 acc

__device__ __forceinline__ unsigned short f2bf(float f) {
    unsigned int u = __float_as_uint(f);
    u += 0x7fffu + ((u >> 16) & 1u);      // round-to-nearest-even
    return (unsigned short)(u >> 16);
}

__device__ __forceinline__ float trilerp(const float* __restrict__ lutS,
                                         float x, float y, float z) {
    int x0 = (int)fminf(fmaxf(floorf(x), 0.0f), 1.0f);
    int y0 = (int)fminf(fmaxf(floorf(y), 0.0f), 1.0f);
    int z0 = (int)fminf(fmaxf(floorf(z), 0.0f), 1.0f);
    float xd = x - (float)x0;
    float yd = y - (float)y0;
    float zd = z - (float)z0;
    int base = x0 * 9 + y0 * 3 + z0;
    float c000 = lutS[base],     c100 = lutS[base + 9];
    float c010 = lutS[base + 3], c110 = lutS[base + 12];
    float c001 = lutS[base + 1], c101 = lutS[base + 10];
    float c011 = lutS[base + 4], c111 = lutS[base + 13];
    float xm = 1.0f - xd, ym = 1.0f - yd;
    float c00 = c000 * xm * ym + c100 * xd * ym + c010 * xm * yd + c110 * xd * yd;
    float c01 = c001 * xm * ym + c101 * xd * ym + c011 * xm * yd + c111 * xd * yd;
    return c00 * (1.0f - zd) + c01 * zd;
}

__global__ __launch_bounds__(512, 4)
void ImageReconstruction_46523085751029_kernel(
        const float* __restrict__ seq,      // [256][2048][256]
        const float* __restrict__ blocks,   // [256][64]
        const float* __restrict__ lut,      // [27]
        const float* __restrict__ gumbel,   // [16][2048][256]
        const int*   __restrict__ fidx,     // [16]
        float*       __restrict__ out)      // [16][256][512]
{
    __shared__ __align__(16) unsigned short E[64 * EPITCH];  // 33792 B; aliased later
    __shared__ float lutS[28];

    const int t    = threadIdx.x;
    const int lane = t & 63;
    const int wave = t >> 6;          // 0..7
    const int ws   = wave & 3;        // N-strip (pixel group of 16)
    const int mh   = wave >> 2;       // M half: tiles {0,1} or {2,3} (x16)
    const int b    = blockIdx.x >> 5;
    const int hb   = blockIdx.x & 31;

    if (t < 27) lutS[t] = lut[t];

    const int f = fidx[b];
    const float* sp = seq    + (size_t)f * (TIL * NB) + (size_t)hb * (64 * NB);
    const float* gp = gumbel + (size_t)b * (TIL * NB) + (size_t)hb * (64 * NB);

    // ---- P1: coalesced load + exp + bf16 pack -> E[tile][n]  (no max-sub: |x|<=~22)
    #pragma unroll 4
    for (int r = 0; r < 8; ++r) {
        int fi = r * 512 + t;                       // float4 index, covers 64*256 floats
        float4 l4 = *(const float4*)(sp + fi * 4);
        float4 g4 = *(const float4*)(gp + fi * 4);
        int tile = fi >> 6;
        int n    = (fi & 63) * 4;
        ushort4 st = make_ushort4(f2bf(__expf(l4.x + g4.x)), f2bf(__expf(l4.y + g4.y)),
                                  f2bf(__expf(l4.z + g4.z)), f2bf(__expf(l4.w + g4.w)));
        *(ushort4*)&E[tile * EPITCH + n] = st;      // 8B store, contiguous per wave
    }

    // ---- B-fragments from global (L2-hot 64 KB), same k-formula as A-frags
    const int g = lane >> 4;       // k-group
    const int c = lane & 15;       // N-index within strip
    s8v bfrag[8];
    #pragma unroll
    for (int ks = 0; ks < 8; ++ks) {
        s8v bf;
        #pragma unroll
        for (int j = 0; j < 8; ++j) {
            float v = blocks[(ks * 32 + g * 8 + j) * 64 + ws * 16 + c];
            bf[j] = (short)f2bf(v);
        }
        bfrag[ks] = bf;
    }
    s8v ones;
    #pragma unroll
    for (int j = 0; j < 8; ++j) ones[j] = (c == 0) ? (short)0x3F80 : (short)0;

    __syncthreads();

    // ---- P2: MFMA. Wave: N-strip ws, M-tiles {mh*2, mh*2+1}, K=256.
    f4v acc[2], accd[2];
    #pragma unroll
    for (int mi = 0; mi < 2; ++mi) { acc[mi] = (f4v)0.0f; accd[mi] = (f4v)0.0f; }

    #pragma unroll
    for (int ks = 0; ks < 8; ++ks) {
        #pragma unroll
        for (int mi = 0; mi < 2; ++mi) {
            int mt = mh * 2 + mi;
            s8v a = *(const s8v*)&E[(mt * 16 + c) * EPITCH + ks * 32 + g * 8];
            acc[mi]  = __builtin_amdgcn_mfma_f32_16x16x32_bf16(a, bfrag[ks], acc[mi],  0, 0, 0);
            accd[mi] = __builtin_amdgcn_mfma_f32_16x16x32_bf16(a, ones,      accd[mi], 0, 0, 0);
        }
    }

    __syncthreads();   // all E reads done; safe to alias

    // ---- normalize (den from accd col 0 of each row, broadcast in 16-lane group)
    float* rows_img = (float*)E;            // [8][512] = 16 KB
    float* rows_f   = (float*)E + 4096;     // [8][512] = 16 KB (total 32 KB <= 33792 B)

    #pragma unroll
    for (int mi = 0; mi < 2; ++mi) {
        #pragma unroll
        for (int rg = 0; rg < 4; ++rg) {
            float den = __shfl(accd[mi][rg], (lane >> 4) * 16);
            float val = acc[mi][rg] * (2.0f / den);
            int row = (mh * 2 + mi) * 16 + g * 4 + rg;  // tile index wb (0..63)
            int p   = ws * 16 + c;                      // pixel 0..63
            int bh  = p >> 3, bw = p & 7;
            rows_img[bh * 512 + row * 8 + bw] = val;
        }
    }
    __syncthreads();

    // ---- Pass 1: horizontal filter at w%8 in {0,7}
    #pragma unroll 2
    for (int pp = 0; pp < 8; ++pp) {
        int pix = pp * 512 + t;
        int bh = pix >> 9, w = pix & 511;
        float cv  = rows_img[bh * 512 + w];
        float res = cv;
        int w8 = w & 7;
        if (w8 == 0 || w8 == 7) {
            int wm = (w > 0)   ? w - 1 : 0;
            int wp = (w < 511) ? w + 1 : 511;
            res = trilerp(lutS, cv, rows_img[bh * 512 + wm], rows_img[bh * 512 + wp]);
        }
        rows_f[bh * 512 + w] = res;
    }
    __syncthreads();

    // ---- Pass 2 (rows h%8 in {0,7}; x-arg = ORIGINAL img per reference) + store
    float* op = out + (size_t)b * (256 * 512) + (size_t)hb * (8 * 512);
    #pragma unroll 2
    for (int pp = 0; pp < 8; ++pp) {
        int pix = pp * 512 + t;
        int bh = pix >> 9, w = pix & 511;
        float gv;
        if (bh == 0 || bh == 7) {
            int wm = (w > 0)   ? w - 1 : 0;
            int wp = (w < 511) ? w + 1 : 511;
            gv = trilerp(lutS, rows_img[bh * 512 + w],
                         rows_f[bh * 512 + wm], rows_f[bh * 512 + wp]);
        } else {
            gv = rows_f[bh * 512 + w];
        }
        op[bh * 512 + w] = 0.5f * gv;
    }
}

extern "C" void kernel_launch(void* const* d_in, const int* in_sizes, int n_in,
                              void* d_out, int out_size, void* d_ws, size_t ws_size,
                              hipStream_t stream) {
    const float* seq    = (const float*)d_in[0];
    const float* blocks = (const float*)d_in[1];
    const float* lut    = (const float*)d_in[2];
    const float* gumbel = (const float*)d_in[3];
    const int*   fidx   = (const int*)d_in[4];
    float* out = (float*)d_out;

    dim3 grid(512);   // 16 batches x 32 tile-rows
    dim3 block(512);
    ImageReconstruction_46523085751029_kernel<<<grid, block, 0, stream>>>(
        seq, blocks, lut, gumbel, fidx, out);
}

// Round 5
// 24.298 us; speedup vs baseline: 1.5635x; 1.0029x over previous
//
#include <hip/hip_runtime.h>

// out[b,h,w] = deblock( 2 * softmax(seq[f[b],t]+gum[b,t]) @ blocks ) / 2
// One WG per (b, hb): 64 tiles x 256 softmax + matvec + row-local deblock.
// 256 thr/WG, launch_bounds(256,4): 4 barrier-independent WGs/CU so one WG's
// compute tail hides under another WG's HBM streaming.
// Matvec via bf16 MFMA 16x16x32; softmax den via ones-column MFMA (col 0).
// A/B-frags use the SAME lane->k formula (HW k-interleave cancels over K);
// relies only on lane&15 <-> M/N and C/D map col=lane&15,row=(lane>>4)*4+reg.
// Filter: pass1 only at boundary columns (w%8 in {0,7}) -> fcol[8][128];
// pass2 reads fval = boundary?fcol:img, x-arg = ORIGINAL img (per reference).

#define NB       256
#define TIL      2048
#define EPITCH   264   // ushort pitch (528 B/row, 16B-aligned, 2-way-free banks)
#define ROWPITCH 520   // float pitch for rows_img

typedef short  s8v __attribute__((ext_vector_type(8)));  // 8 bf16 = 4 VGPR
typedef float  f4v __attribute__((ext_vector_type(4)));  // 4 f32 acc

__device__ __forceinline__ unsigned short f2bf(float f) {
    unsigned int u = __float_as_uint(f);
    u += 0x7fffu + ((u >> 16) & 1u);      // round-to-nearest-even
    return (unsigned short)(u >> 16);
}

__device__ __forceinline__ unsigned int pk2(float a, float b) {
    return (unsigned int)f2bf(a) | ((unsigned int)f2bf(b) << 16);  // low=a, high=b
}

__device__ __forceinline__ float trilerp(const float* __restrict__ lutS,
                                         float x, float y, float z) {
    int x0 = (int)fminf(fmaxf(floorf(x), 0.0f), 1.0f);
    int y0 = (int)fminf(fmaxf(floorf(y), 0.0f), 1.0f);
    int z0 = (int)fminf(fmaxf(floorf(z), 0.0f), 1.0f);
    float xd = x - (float)x0;
    float yd = y - (float)y0;
    float zd = z - (float)z0;
    int base = x0 * 9 + y0 * 3 + z0;
    float c000 = lutS[base],     c100 = lutS[base + 9];
    float c010 = lutS[base + 3], c110 = lutS[base + 12];
    float c001 = lutS[base + 1], c101 = lutS[base + 10];
    float c011 = lutS[base + 4], c111 = lutS[base + 13];
    float xm = 1.0f - xd, ym = 1.0f - yd;
    float c00 = c000 * xm * ym + c100 * xd * ym + c010 * xm * yd + c110 * xd * yd;
    float c01 = c001 * xm * ym + c101 * xd * ym + c011 * xm * yd + c111 * xd * yd;
    return c00 * (1.0f - zd) + c01 * zd;
}

__device__ __forceinline__ float fval(const float* __restrict__ row,
                                      const float* __restrict__ fcolr, int x) {
    int x8 = x & 7;
    if (x8 == 0 || x8 == 7) return fcolr[(x >> 3) * 2 + (x8 == 7)];
    return row[x];
}

__global__ __launch_bounds__(256, 4)
void ImageReconstruction_46523085751029_kernel(
        const float* __restrict__ seq,      // [256][2048][256]
        const float* __restrict__ blocks,   // [256][64]
        const float* __restrict__ lut,      // [27]
        const float* __restrict__ gumbel,   // [16][2048][256]
        const int*   __restrict__ fidx,     // [16]
        float*       __restrict__ out)      // [16][256][512]
{
    __shared__ __align__(16) unsigned short E[64 * EPITCH];  // 33792 B; aliased later
    __shared__ float lutS[28];

    const int t    = threadIdx.x;
    const int lane = t & 63;
    const int wave = t >> 6;          // 0..3 -> N-strip
    const int b    = blockIdx.x >> 5;
    const int hb   = blockIdx.x & 31;

    if (t < 27) lutS[t] = lut[t];

    const int f = fidx[b];
    const float* sp = seq    + (size_t)f * (TIL * NB) + (size_t)hb * (64 * NB);
    const float* gp = gumbel + (size_t)b * (TIL * NB) + (size_t)hb * (64 * NB);

    // ---- P1: coalesced load + exp + bf16 pack -> E[tile][n]  (no max-sub: |x|<=~22)
    #pragma unroll 2
    for (int r = 0; r < 16; ++r) {
        int fi = r * 256 + t;                       // float4 idx over 64*256 floats
        float4 l4 = *(const float4*)(sp + fi * 4);
        float4 g4 = *(const float4*)(gp + fi * 4);
        int tile = fi >> 6;
        int n    = (fi & 63) * 4;
        unsigned int u0 = pk2(__expf(l4.x + g4.x), __expf(l4.y + g4.y));
        unsigned int u1 = pk2(__expf(l4.z + g4.z), __expf(l4.w + g4.w));
        *(uint2*)&E[tile * EPITCH + n] = make_uint2(u0, u1);   // 8B aligned
    }

    // ---- B-fragments from global (L2-hot 64 KB), same k-formula as A-frags
    const int g = lane >> 4;       // k-group
    const int c = lane & 15;       // N-index within strip
    const float* bp = blocks + wave * 16 + c;      // column base
    s8v bfrag[8];
    #pragma unroll
    for (int ks = 0; ks < 8; ++ks) {
        int k0 = ks * 32 + g * 8;
        unsigned int u[4];
        #pragma unroll
        for (int jj = 0; jj < 4; ++jj)
            u[jj] = pk2(bp[(k0 + 2 * jj) * 64], bp[(k0 + 2 * jj + 1) * 64]);
        int4 iv = make_int4(u[0], u[1], u[2], u[3]);
        bfrag[ks] = __builtin_bit_cast(s8v, iv);
    }
    s8v ones;
    {
        unsigned int uo = (c == 0) ? 0x3F803F80u : 0u;
        int4 iv = make_int4(uo, uo, uo, uo);
        ones = __builtin_bit_cast(s8v, iv);
    }

    __syncthreads();

    // ---- P2: MFMA. Wave: N-strip = wave, all 4 M-tiles, K=256.
    f4v acc[4], accd[4];
    #pragma unroll
    for (int mt = 0; mt < 4; ++mt) { acc[mt] = (f4v)0.0f; accd[mt] = (f4v)0.0f; }

    #pragma unroll
    for (int ks = 0; ks < 8; ++ks) {
        #pragma unroll
        for (int mt = 0; mt < 4; ++mt) {
            s8v a = *(const s8v*)&E[(mt * 16 + c) * EPITCH + ks * 32 + g * 8];
            acc[mt]  = __builtin_amdgcn_mfma_f32_16x16x32_bf16(a, bfrag[ks], acc[mt],  0, 0, 0);
            accd[mt] = __builtin_amdgcn_mfma_f32_16x16x32_bf16(a, ones,      accd[mt], 0, 0, 0);
        }
    }

    __syncthreads();   // all E reads done; safe to alias

    // ---- normalize (den from accd col 0 of each row) -> rows_img
    float* rows_img = (float*)E;                    // [8][520] = 16640 B
    float* fcol     = (float*)E + 8 * ROWPITCH;     // [8][128] =  4096 B (tot 20736)

    #pragma unroll
    for (int mt = 0; mt < 4; ++mt) {
        #pragma unroll
        for (int rg = 0; rg < 4; ++rg) {
            float den = __shfl(accd[mt][rg], (lane >> 4) * 16);
            float val = acc[mt][rg] * (2.0f / den);
            int row = mt * 16 + g * 4 + rg;      // tile index wb (0..63)
            int p   = wave * 16 + c;             // pixel 0..63 in tile
            int bh  = p >> 3, bw = p & 7;
            rows_img[bh * ROWPITCH + row * 8 + bw] = val;
        }
    }
    __syncthreads();

    // ---- Pass 1: horizontal filter ONLY at boundary columns (w%8 in {0,7})
    #pragma unroll
    for (int it = 0; it < 4; ++it) {
        int idx = it * 256 + t;                  // 0..1023
        int bh = idx >> 7, ci = idx & 127;
        int w  = (ci >> 1) * 8 + ((ci & 1) ? 7 : 0);
        const float* row = rows_img + bh * ROWPITCH;
        int wm = (w > 0)   ? w - 1 : 0;
        int wp = (w < 511) ? w + 1 : 511;
        fcol[bh * 128 + ci] = trilerp(lutS, row[w], row[wm], row[wp]);
    }
    __syncthreads();

    // ---- Pass 2 + store (rows h%8 in {0,7} filter; x-arg = ORIGINAL img)
    float* op = out + (size_t)b * (256 * 512) + (size_t)hb * (8 * 512);
    #pragma unroll 2
    for (int it = 0; it < 16; ++it) {
        int pix = it * 256 + t;
        int bh = pix >> 9, w = pix & 511;        // bh wave-uniform per it
        const float* row = rows_img + bh * ROWPITCH;
        const float* fr  = fcol + bh * 128;
        float gv;
        if (bh == 0 || bh == 7) {
            int wm = (w > 0)   ? w - 1 : 0;
            int wp = (w < 511) ? w + 1 : 511;
            gv = trilerp(lutS, row[w], fval(row, fr, wm), fval(row, fr, wp));
        } else {
            gv = fval(row, fr, w);
        }
        op[bh * 512 + w] = 0.5f * gv;
    }
}

extern "C" void kernel_launch(void* const* d_in, const int* in_sizes, int n_in,
                              void* d_out, int out_size, void* d_ws, size_t ws_size,
                              hipStream_t stream) {
    const float* seq    = (const float*)d_in[0];
    const float* blocks = (const float*)d_in[1];
    const float* lut    = (const float*)d_in[2];
    const float* gumbel = (const float*)d_in[3];
    const int*   fidx   = (const int*)d_in[4];
    float* out = (float*)d_out;

    dim3 grid(512);   // 16 batches x 32 tile-rows
    dim3 block(256);
    ImageReconstruction_46523085751029_kernel<<<grid, block, 0, stream>>>(
        seq, blocks, lut, gumbel, fidx, out);
}

// Round 6
// 24.193 us; speedup vs baseline: 1.5703x; 1.0043x over previous
//
#include <hip/hip_runtime.h>

// out[b,h,w] = deblock( 2 * softmax(seq[f[b],t]+gum[b,t]) @ blocks ) / 2
// One WG per (b, hb): 64 tiles x 256 softmax + matvec + row-local deblock.
// P1 burst-issues ALL 32 float4 loads (512 B/thread) before consuming:
// 256 KB/CU in flight >> BW*latency (~15 KB/CU) -> HBM-saturating MLP.
// launch_bounds(256,2): VGPR cap 256 (grid is pinned at 2 WGs/CU anyway).
// Matvec via bf16 MFMA 16x16x32; softmax den via ones-column MFMA (col 0).
// A/B-frags use the SAME lane->k formula (HW k-interleave cancels over K);
// relies only on lane&15 <-> M/N and C/D map col=lane&15,row=(lane>>4)*4+reg.
// Filter: pass1 only at boundary columns (w%8 in {0,7}) -> fcol[8][128];
// pass2 reads fval = boundary?fcol:img, x-arg = ORIGINAL img (per reference).

#define NB       256
#define TIL      2048
#define EPITCH   264   // ushort pitch (528 B/row, 16B-aligned, 2-way-free banks)
#define ROWPITCH 520   // float pitch for rows_img

typedef short  s8v __attribute__((ext_vector_type(8)));  // 8 bf16 = 4 VGPR
typedef float  f4v __attribute__((ext_vector_type(4)));  // 4 f32 acc

__device__ __forceinline__ unsigned short f2bf(float f) {
    unsigned int u = __float_as_uint(f);
    u += 0x7fffu + ((u >> 16) & 1u);      // round-to-nearest-even
    return (unsigned short)(u >> 16);
}

__device__ __forceinline__ unsigned int pk2(float a, float b) {
    return (unsigned int)f2bf(a) | ((unsigned int)f2bf(b) << 16);  // low=a, high=b
}

__device__ __forceinline__ float trilerp(const float* __restrict__ lutS,
                                         float x, float y, float z) {
    int x0 = (int)fminf(fmaxf(floorf(x), 0.0f), 1.0f);
    int y0 = (int)fminf(fmaxf(floorf(y), 0.0f), 1.0f);
    int z0 = (int)fminf(fmaxf(floorf(z), 0.0f), 1.0f);
    float xd = x - (float)x0;
    float yd = y - (float)y0;
    float zd = z - (float)z0;
    int base = x0 * 9 + y0 * 3 + z0;
    float c000 = lutS[base],     c100 = lutS[base + 9];
    float c010 = lutS[base + 3], c110 = lutS[base + 12];
    float c001 = lutS[base + 1], c101 = lutS[base + 10];
    float c011 = lutS[base + 4], c111 = lutS[base + 13];
    float xm = 1.0f - xd, ym = 1.0f - yd;
    float c00 = c000 * xm * ym + c100 * xd * ym + c010 * xm * yd + c110 * xd * yd;
    float c01 = c001 * xm * ym + c101 * xd * ym + c011 * xm * yd + c111 * xd * yd;
    return c00 * (1.0f - zd) + c01 * zd;
}

__device__ __forceinline__ float fval(const float* __restrict__ row,
                                      const float* __restrict__ fcolr, int x) {
    int x8 = x & 7;
    if (x8 == 0 || x8 == 7) return fcolr[(x >> 3) * 2 + (x8 == 7)];
    return row[x];
}

__global__ __launch_bounds__(256, 2)
void ImageReconstruction_46523085751029_kernel(
        const float* __restrict__ seq,      // [256][2048][256]
        const float* __restrict__ blocks,   // [256][64]
        const float* __restrict__ lut,      // [27]
        const float* __restrict__ gumbel,   // [16][2048][256]
        const int*   __restrict__ fidx,     // [16]
        float*       __restrict__ out)      // [16][256][512]
{
    __shared__ __align__(16) unsigned short E[64 * EPITCH];  // 33792 B; aliased later
    __shared__ float lutS[28];

    const int t    = threadIdx.x;
    const int lane = t & 63;
    const int wave = t >> 6;          // 0..3 -> N-strip
    const int b    = blockIdx.x >> 5;
    const int hb   = blockIdx.x & 31;

    if (t < 27) lutS[t] = lut[t];

    const int f = fidx[b];
    const float* sp = seq    + (size_t)f * (TIL * NB) + (size_t)hb * (64 * NB);
    const float* gp = gumbel + (size_t)b * (TIL * NB) + (size_t)hb * (64 * NB);

    // ---- P1a: burst-issue ALL loads (full unroll, compile-time indices ->
    //           registers; 32 outstanding float4 loads per thread)
    float4 lq[16], gq[16];
    #pragma unroll
    for (int r = 0; r < 16; ++r)
        lq[r] = *(const float4*)(sp + (r * 256 + t) * 4);
    #pragma unroll
    for (int r = 0; r < 16; ++r)
        gq[r] = *(const float4*)(gp + (r * 256 + t) * 4);

    // ---- P1b: exp + bf16 pack -> E[tile][n]  (no max-sub: |x|<=~22, f32-safe)
    #pragma unroll
    for (int r = 0; r < 16; ++r) {
        int fi = r * 256 + t;                       // float4 idx over 64*256 floats
        int tile = fi >> 6;
        int n    = (fi & 63) * 4;
        unsigned int u0 = pk2(__expf(lq[r].x + gq[r].x), __expf(lq[r].y + gq[r].y));
        unsigned int u1 = pk2(__expf(lq[r].z + gq[r].z), __expf(lq[r].w + gq[r].w));
        *(uint2*)&E[tile * EPITCH + n] = make_uint2(u0, u1);   // 8B aligned
    }

    // ---- B-fragments from global (L2-hot 64 KB), same k-formula as A-frags
    const int g = lane >> 4;       // k-group
    const int c = lane & 15;       // N-index within strip
    const float* bp = blocks + wave * 16 + c;      // column base
    s8v bfrag[8];
    #pragma unroll
    for (int ks = 0; ks < 8; ++ks) {
        int k0 = ks * 32 + g * 8;
        unsigned int u[4];
        #pragma unroll
        for (int jj = 0; jj < 4; ++jj)
            u[jj] = pk2(bp[(k0 + 2 * jj) * 64], bp[(k0 + 2 * jj + 1) * 64]);
        int4 iv = make_int4(u[0], u[1], u[2], u[3]);
        bfrag[ks] = __builtin_bit_cast(s8v, iv);
    }
    s8v ones;
    {
        unsigned int uo = (c == 0) ? 0x3F803F80u : 0u;
        int4 iv = make_int4(uo, uo, uo, uo);
        ones = __builtin_bit_cast(s8v, iv);
    }

    __syncthreads();

    // ---- P2: MFMA. Wave: N-strip = wave, all 4 M-tiles, K=256.
    f4v acc[4], accd[4];
    #pragma unroll
    for (int mt = 0; mt < 4; ++mt) { acc[mt] = (f4v)0.0f; accd[mt] = (f4v)0.0f; }

    #pragma unroll
    for (int ks = 0; ks < 8; ++ks) {
        #pragma unroll
        for (int mt = 0; mt < 4; ++mt) {
            s8v a = *(const s8v*)&E[(mt * 16 + c) * EPITCH + ks * 32 + g * 8];
            acc[mt]  = __builtin_amdgcn_mfma_f32_16x16x32_bf16(a, bfrag[ks], acc[mt],  0, 0, 0);
            accd[mt] = __builtin_amdgcn_mfma_f32_16x16x32_bf16(a, ones,      accd[mt], 0, 0, 0);
        }
    }

    __syncthreads();   // all E reads done; safe to alias

    // ---- normalize (den from accd col 0 of each row) -> rows_img
    float* rows_img = (float*)E;                    // [8][520] = 16640 B
    float* fcol     = (float*)E + 8 * ROWPITCH;     // [8][128] =  4096 B (tot 20736)

    #pragma unroll
    for (int mt = 0; mt < 4; ++mt) {
        #pragma unroll
        for (int rg = 0; rg < 4; ++rg) {
            float den = __shfl(accd[mt][rg], (lane >> 4) * 16);
            float val = acc[mt][rg] * (2.0f / den);
            int row = mt * 16 + g * 4 + rg;      // tile index wb (0..63)
            int p   = wave * 16 + c;             // pixel 0..63 in tile
            int bh  = p >> 3, bw = p & 7;
            rows_img[bh * ROWPITCH + row * 8 + bw] = val;
        }
    }
    __syncthreads();

    // ---- Pass 1: horizontal filter ONLY at boundary columns (w%8 in {0,7})
    #pragma unroll
    for (int it = 0; it < 4; ++it) {
        int idx = it * 256 + t;                  // 0..1023
        int bh = idx >> 7, ci = idx & 127;
        int w  = (ci >> 1) * 8 + ((ci & 1) ? 7 : 0);
        const float* row = rows_img + bh * ROWPITCH;
        int wm = (w > 0)   ? w - 1 : 0;
        int wp = (w < 511) ? w + 1 : 511;
        fcol[bh * 128 + ci] = trilerp(lutS, row[w], row[wm], row[wp]);
    }
    __syncthreads();

    // ---- Pass 2 + store (rows h%8 in {0,7} filter; x-arg = ORIGINAL img)
    float* op = out + (size_t)b * (256 * 512) + (size_t)hb * (8 * 512);
    #pragma unroll 2
    for (int it = 0; it < 16; ++it) {
        int pix = it * 256 + t;
        int bh = pix >> 9, w = pix & 511;        // bh wave-uniform per it
        const float* row = rows_img + bh * ROWPITCH;
        const float* fr  = fcol + bh * 128;
        float gv;
        if (bh == 0 || bh == 7) {
            int wm = (w > 0)   ? w - 1 : 0;
            int wp = (w < 511) ? w + 1 : 511;
            gv = trilerp(lutS, row[w], fval(row, fr, wm), fval(row, fr, wp));
        } else {
            gv = fval(row, fr, w);
        }
        op[bh * 512 + w] = 0.5f * gv;
    }
}

extern "C" void kernel_launch(void* const* d_in, const int* in_sizes, int n_in,
                              void* d_out, int out_size, void* d_ws, size_t ws_size,
                              hipStream_t stream) {
    const float* seq    = (const float*)d_in[0];
    const float* blocks = (const float*)d_in[1];
    const float* lut    = (const float*)d_in[2];
    const float* gumbel = (const float*)d_in[3];
    const int*   fidx   = (const int*)d_in[4];
    float* out = (float*)d_out;

    dim3 grid(512);   // 16 batches x 32 tile-rows
    dim3 block(256);
    ImageReconstruction_46523085751029_kernel<<<grid, block, 0, stream>>>(
        seq, blocks, lut, gumbel, fidx, out);
}

// Round 7
// 20.335 us; speedup vs baseline: 1.8682x; 1.1897x over previous
//
#include <hip/hip_runtime.h>

// out[b,h,w] = deblock( 2 * softmax(seq[f[b],t]+gum[b,t]) @ blocks ) / 2
// One WG per (b, hb): 64 tiles x 256 softmax + matvec + row-local deblock.
// R7 change (only): NONTEMPORAL loads for the seq/gumbel streams and
// nontemporal stores for out — single-use streaming data; bypassing L2/L3
// allocation removes interaction with the harness's 2-GB poison-fill
// writeback and any L3-path rate limit. Everything else identical to R6.
// Matvec via bf16 MFMA 16x16x32; softmax den via ones-column MFMA (col 0).
// Filter: pass1 only at boundary cols -> fcol; pass2 x-arg = ORIGINAL img.

#define NB       256
#define TIL      2048
#define EPITCH   264   // ushort pitch (528 B/row, 16B-aligned, 2-way-free banks)
#define ROWPITCH 520   // float pitch for rows_img

typedef short  s8v __attribute__((ext_vector_type(8)));  // 8 bf16 = 4 VGPR
typedef float  f4v __attribute__((ext_vector_type(4)));  // 4 f32 acc

__device__ __forceinline__ unsigned short f2bf(float f) {
    unsigned int u = __float_as_uint(f);
    u += 0x7fffu + ((u >> 16) & 1u);      // round-to-nearest-even
    return (unsigned short)(u >> 16);
}

__device__ __forceinline__ unsigned int pk2(float a, float b) {
    return (unsigned int)f2bf(a) | ((unsigned int)f2bf(b) << 16);  // low=a, high=b
}

__device__ __forceinline__ float4 ldnt4(const float* p) {
    float4 v;
    v.x = __builtin_nontemporal_load(p + 0);
    v.y = __builtin_nontemporal_load(p + 1);
    v.z = __builtin_nontemporal_load(p + 2);
    v.w = __builtin_nontemporal_load(p + 3);
    return v;   // clang folds to global_load_dwordx4 nt
}

__device__ __forceinline__ float trilerp(const float* __restrict__ lutS,
                                         float x, float y, float z) {
    int x0 = (int)fminf(fmaxf(floorf(x), 0.0f), 1.0f);
    int y0 = (int)fminf(fmaxf(floorf(y), 0.0f), 1.0f);
    int z0 = (int)fminf(fmaxf(floorf(z), 0.0f), 1.0f);
    float xd = x - (float)x0;
    float yd = y - (float)y0;
    float zd = z - (float)z0;
    int base = x0 * 9 + y0 * 3 + z0;
    float c000 = lutS[base],     c100 = lutS[base + 9];
    float c010 = lutS[base + 3], c110 = lutS[base + 12];
    float c001 = lutS[base + 1], c101 = lutS[base + 10];
    float c011 = lutS[base + 4], c111 = lutS[base + 13];
    float xm = 1.0f - xd, ym = 1.0f - yd;
    float c00 = c000 * xm * ym + c100 * xd * ym + c010 * xm * yd + c110 * xd * yd;
    float c01 = c001 * xm * ym + c101 * xd * ym + c011 * xm * yd + c111 * xd * yd;
    return c00 * (1.0f - zd) + c01 * zd;
}

__device__ __forceinline__ float fval(const float* __restrict__ row,
                                      const float* __restrict__ fcolr, int x) {
    int x8 = x & 7;
    if (x8 == 0 || x8 == 7) return fcolr[(x >> 3) * 2 + (x8 == 7)];
    return row[x];
}

__global__ __launch_bounds__(256, 2)
void ImageReconstruction_46523085751029_kernel(
        const float* __restrict__ seq,      // [256][2048][256]
        const float* __restrict__ blocks,   // [256][64]
        const float* __restrict__ lut,      // [27]
        const float* __restrict__ gumbel,   // [16][2048][256]
        const int*   __restrict__ fidx,     // [16]
        float*       __restrict__ out)      // [16][256][512]
{
    __shared__ __align__(16) unsigned short E[64 * EPITCH];  // 33792 B; aliased later
    __shared__ float lutS[28];

    const int t    = threadIdx.x;
    const int lane = t & 63;
    const int wave = t >> 6;          // 0..3 -> N-strip
    const int b    = blockIdx.x >> 5;
    const int hb   = blockIdx.x & 31;

    if (t < 27) lutS[t] = lut[t];

    const int f = fidx[b];
    const float* sp = seq    + (size_t)f * (TIL * NB) + (size_t)hb * (64 * NB);
    const float* gp = gumbel + (size_t)b * (TIL * NB) + (size_t)hb * (64 * NB);

    // ---- P1a: burst-issue ALL loads (nontemporal: no L2/L3 allocation)
    float4 lq[16], gq[16];
    #pragma unroll
    for (int r = 0; r < 16; ++r)
        lq[r] = ldnt4(sp + (r * 256 + t) * 4);
    #pragma unroll
    for (int r = 0; r < 16; ++r)
        gq[r] = ldnt4(gp + (r * 256 + t) * 4);

    // ---- P1b: exp + bf16 pack -> E[tile][n]  (no max-sub: |x|<=~22, f32-safe)
    #pragma unroll
    for (int r = 0; r < 16; ++r) {
        int fi = r * 256 + t;                       // float4 idx over 64*256 floats
        int tile = fi >> 6;
        int n    = (fi & 63) * 4;
        unsigned int u0 = pk2(__expf(lq[r].x + gq[r].x), __expf(lq[r].y + gq[r].y));
        unsigned int u1 = pk2(__expf(lq[r].z + gq[r].z), __expf(lq[r].w + gq[r].w));
        *(uint2*)&E[tile * EPITCH + n] = make_uint2(u0, u1);   // 8B aligned
    }

    // ---- B-fragments from global (L2-hot 64 KB), same k-formula as A-frags
    const int g = lane >> 4;       // k-group
    const int c = lane & 15;       // N-index within strip
    const float* bp = blocks + wave * 16 + c;      // column base
    s8v bfrag[8];
    #pragma unroll
    for (int ks = 0; ks < 8; ++ks) {
        int k0 = ks * 32 + g * 8;
        unsigned int u[4];
        #pragma unroll
        for (int jj = 0; jj < 4; ++jj)
            u[jj] = pk2(bp[(k0 + 2 * jj) * 64], bp[(k0 + 2 * jj + 1) * 64]);
        int4 iv = make_int4(u[0], u[1], u[2], u[3]);
        bfrag[ks] = __builtin_bit_cast(s8v, iv);
    }
    s8v ones;
    {
        unsigned int uo = (c == 0) ? 0x3F803F80u : 0u;
        int4 iv = make_int4(uo, uo, uo, uo);
        ones = __builtin_bit_cast(s8v, iv);
    }

    __syncthreads();

    // ---- P2: MFMA. Wave: N-strip = wave, all 4 M-tiles, K=256.
    f4v acc[4], accd[4];
    #pragma unroll
    for (int mt = 0; mt < 4; ++mt) { acc[mt] = (f4v)0.0f; accd[mt] = (f4v)0.0f; }

    #pragma unroll
    for (int ks = 0; ks < 8; ++ks) {
        #pragma unroll
        for (int mt = 0; mt < 4; ++mt) {
            s8v a = *(const s8v*)&E[(mt * 16 + c) * EPITCH + ks * 32 + g * 8];
            acc[mt]  = __builtin_amdgcn_mfma_f32_16x16x32_bf16(a, bfrag[ks], acc[mt],  0, 0, 0);
            accd[mt] = __builtin_amdgcn_mfma_f32_16x16x32_bf16(a, ones,      accd[mt], 0, 0, 0);
        }
    }

    __syncthreads();   // all E reads done; safe to alias

    // ---- normalize (den from accd col 0 of each row) -> rows_img
    float* rows_img = (float*)E;                    // [8][520] = 16640 B
    float* fcol     = (float*)E + 8 * ROWPITCH;     // [8][128] =  4096 B (tot 20736)

    #pragma unroll
    for (int mt = 0; mt < 4; ++mt) {
        #pragma unroll
        for (int rg = 0; rg < 4; ++rg) {
            float den = __shfl(accd[mt][rg], (lane >> 4) * 16);
            float val = acc[mt][rg] * (2.0f / den);
            int row = mt * 16 + g * 4 + rg;      // tile index wb (0..63)
            int p   = wave * 16 + c;             // pixel 0..63 in tile
            int bh  = p >> 3, bw = p & 7;
            rows_img[bh * ROWPITCH + row * 8 + bw] = val;
        }
    }
    __syncthreads();

    // ---- Pass 1: horizontal filter ONLY at boundary columns (w%8 in {0,7})
    #pragma unroll
    for (int it = 0; it < 4; ++it) {
        int idx = it * 256 + t;                  // 0..1023
        int bh = idx >> 7, ci = idx & 127;
        int w  = (ci >> 1) * 8 + ((ci & 1) ? 7 : 0);
        const float* row = rows_img + bh * ROWPITCH;
        int wm = (w > 0)   ? w - 1 : 0;
        int wp = (w < 511) ? w + 1 : 511;
        fcol[bh * 128 + ci] = trilerp(lutS, row[w], row[wm], row[wp]);
    }
    __syncthreads();

    // ---- Pass 2 + store (rows h%8 in {0,7} filter; x-arg = ORIGINAL img)
    float* op = out + (size_t)b * (256 * 512) + (size_t)hb * (8 * 512);
    #pragma unroll 2
    for (int it = 0; it < 16; ++it) {
        int pix = it * 256 + t;
        int bh = pix >> 9, w = pix & 511;        // bh wave-uniform per it
        const float* row = rows_img + bh * ROWPITCH;
        const float* fr  = fcol + bh * 128;
        float gv;
        if (bh == 0 || bh == 7) {
            int wm = (w > 0)   ? w - 1 : 0;
            int wp = (w < 511) ? w + 1 : 511;
            gv = trilerp(lutS, row[w], fval(row, fr, wm), fval(row, fr, wp));
        } else {
            gv = fval(row, fr, w);
        }
        __builtin_nontemporal_store(0.5f * gv, op + bh * 512 + w);
    }
}

extern "C" void kernel_launch(void* const* d_in, const int* in_sizes, int n_in,
                              void* d_out, int out_size, void* d_ws, size_t ws_size,
                              hipStream_t stream) {
    const float* seq    = (const float*)d_in[0];
    const float* blocks = (const float*)d_in[1];
    const float* lut    = (const float*)d_in[2];
    const float* gumbel = (const float*)d_in[3];
    const int*   fidx   = (const int*)d_in[4];
    float* out = (float*)d_out;

    dim3 grid(512);   // 16 batches x 32 tile-rows
    dim3 block(256);
    ImageReconstruction_46523085751029_kernel<<<grid, block, 0, stream>>>(
        seq, blocks, lut, gumbel, fidx, out);
}